// Round 1
// baseline (6731.782 us; speedup 1.0000x reference)
//
#include <hip/hip_runtime.h>

// CapsAll: r-head structured self-attention -> capsule votes -> dynamic routing.
// B=128, T=256, U2=1024, DA=512, R=8, SC=128, OA=16, NR=3.
//
// Pipeline (all fp32, VALU-bound; no fp32 MFMA exists on CDNA4):
//   K1 (per r, b-chunk): hbar = relu(x_b @ WS1_r^T)            [bc*256, 512]
//   K2 (per r, b-chunk): scores = hbar @ WS2_r^T (held in regs),
//                        softmax over t, m = (sum_t e*x)/denom  -> m[r,b,1024]
//   K3: votes = m_r @ cw_r                                      -> votes[r,b,2048]
//   K4: dynamic routing (3 iters) + squash + final norms        -> out[b,128]
//
// Workspace: m 4MB @0, votes 8MB @4MB, hbar chunk @16MB (b-chunked to fit ws).

#define T_ 256
#define U2_ 1024
#define DA_ 512

// ---------------- K1: C[m][n] = relu(sum_k A[m][k]*B[n][k]) ----------------
// A = x chunk [M x 1024] lda=1024, B = WS1_r [512 x 1024] (N,K layout),
// C = hbar [M x 512]. BM=BN=128, BK=16, 256 thr, 8x8 micro-tile.
__global__ __launch_bounds__(256) void k1_hbar(const float* __restrict__ A,
                                               const float* __restrict__ Bm,
                                               float* __restrict__ C) {
    __shared__ float As[16][132];
    __shared__ float Bs[16][132];
    const int tid = threadIdx.x;
    const int m0 = blockIdx.y * 128;
    const int n0 = blockIdx.x * 128;
    const int ty = tid >> 4, tx = tid & 15;
    const int k4 = (tid & 3) * 4, row = tid >> 2;  // row 0..63

    float acc[8][8];
#pragma unroll
    for (int i = 0; i < 8; i++)
#pragma unroll
        for (int j = 0; j < 8; j++) acc[i][j] = 0.f;

    for (int k0 = 0; k0 < 1024; k0 += 16) {
#pragma unroll
        for (int rr = 0; rr < 2; rr++) {
            const int m = row + rr * 64;
            float4 av = *(const float4*)(A + (size_t)(m0 + m) * 1024 + k0 + k4);
            As[k4 + 0][m] = av.x; As[k4 + 1][m] = av.y;
            As[k4 + 2][m] = av.z; As[k4 + 3][m] = av.w;
            float4 bv = *(const float4*)(Bm + (size_t)(n0 + m) * 1024 + k0 + k4);
            Bs[k4 + 0][m] = bv.x; Bs[k4 + 1][m] = bv.y;
            Bs[k4 + 2][m] = bv.z; Bs[k4 + 3][m] = bv.w;
        }
        __syncthreads();
#pragma unroll
        for (int k = 0; k < 16; k++) {
            float a[8], b[8];
            *(float4*)(a)     = *(const float4*)(&As[k][ty * 8]);
            *(float4*)(a + 4) = *(const float4*)(&As[k][ty * 8 + 4]);
            *(float4*)(b)     = *(const float4*)(&Bs[k][tx * 8]);
            *(float4*)(b + 4) = *(const float4*)(&Bs[k][tx * 8 + 4]);
#pragma unroll
            for (int i = 0; i < 8; i++)
#pragma unroll
                for (int j = 0; j < 8; j++) acc[i][j] += a[i] * b[j];
        }
        __syncthreads();
    }
#pragma unroll
    for (int i = 0; i < 8; i++) {
        const int m = m0 + ty * 8 + i;
#pragma unroll
        for (int j = 0; j < 8; j += 4) {
            float4 v;
            v.x = fmaxf(acc[i][j + 0], 0.f);
            v.y = fmaxf(acc[i][j + 1], 0.f);
            v.z = fmaxf(acc[i][j + 2], 0.f);
            v.w = fmaxf(acc[i][j + 3], 0.f);
            *(float4*)(C + (size_t)m * 512 + n0 + tx * 8 + j) = v;
        }
    }
}

// ------- K2: scores tile [256 t x 64 u] in regs, softmax over t, emit m -------
// Hb = hbar chunk base; W2 = WS2_r [1024 x 512] (N,K layout); x full input.
// grid = (16 u-blocks, bc). BM=256(=T), BN=64, BK=16, 8x8 micro, thread grid 32x8.
__global__ __launch_bounds__(256) void k2_scores_m(const float* __restrict__ Hb,
                                                   const float* __restrict__ W2,
                                                   const float* __restrict__ x,
                                                   float* __restrict__ m_out,
                                                   int b0, int r) {
    __shared__ float As[16 * 260];
    __shared__ float Bs[16 * 68];
    __shared__ float red[32 * 64];
    __shared__ float red2[32 * 64];
    __shared__ float colmax[64];

    const int tid = threadIdx.x;
    const int b_local = blockIdx.y;
    const int b = b0 + b_local;
    const int u0 = blockIdx.x * 64;
    const float* Ab = Hb + (size_t)b_local * 256 * 512;
    const int ty = tid >> 3, tx = tid & 7;      // 32 x 8 thread grid
    const int k4 = (tid & 3) * 4, rw = tid >> 2;  // loaders

    float acc[8][8];
#pragma unroll
    for (int i = 0; i < 8; i++)
#pragma unroll
        for (int j = 0; j < 8; j++) acc[i][j] = 0.f;

    for (int k0 = 0; k0 < 512; k0 += 16) {
#pragma unroll
        for (int rr = 0; rr < 4; rr++) {
            const int m = rw + rr * 64;
            float4 av = *(const float4*)(Ab + (size_t)m * 512 + k0 + k4);
            As[(k4 + 0) * 260 + m] = av.x; As[(k4 + 1) * 260 + m] = av.y;
            As[(k4 + 2) * 260 + m] = av.z; As[(k4 + 3) * 260 + m] = av.w;
        }
        {
            float4 bv = *(const float4*)(W2 + (size_t)(u0 + rw) * 512 + k0 + k4);
            Bs[(k4 + 0) * 68 + rw] = bv.x; Bs[(k4 + 1) * 68 + rw] = bv.y;
            Bs[(k4 + 2) * 68 + rw] = bv.z; Bs[(k4 + 3) * 68 + rw] = bv.w;
        }
        __syncthreads();
#pragma unroll
        for (int k = 0; k < 16; k++) {
            float a[8], b[8];
            *(float4*)(a)     = *(const float4*)(As + k * 260 + ty * 8);
            *(float4*)(a + 4) = *(const float4*)(As + k * 260 + ty * 8 + 4);
            *(float4*)(b)     = *(const float4*)(Bs + k * 68 + tx * 8);
            *(float4*)(b + 4) = *(const float4*)(Bs + k * 68 + tx * 8 + 4);
#pragma unroll
            for (int i = 0; i < 8; i++)
#pragma unroll
                for (int j = 0; j < 8; j++) acc[i][j] += a[i] * b[j];
        }
        __syncthreads();
    }

    // ---- column-softmax over t (rows), then m[u] = sum_t e*x / sum_t e ----
    // 1) per-thread max over its 8 t's, per u column
#pragma unroll
    for (int j = 0; j < 8; j++) {
        float m8 = acc[0][j];
#pragma unroll
        for (int i = 1; i < 8; i++) m8 = fmaxf(m8, acc[i][j]);
        red[ty * 64 + tx * 8 + j] = m8;
    }
    __syncthreads();
    if (tid < 64) {
        float m = red[tid];
        for (int yy = 1; yy < 32; yy++) m = fmaxf(m, red[yy * 64 + tid]);
        colmax[tid] = m;
    }
    __syncthreads();

    float cm[8], dsum[8], pm[8];
#pragma unroll
    for (int j = 0; j < 8; j++) { cm[j] = colmax[tx * 8 + j]; dsum[j] = 0.f; pm[j] = 0.f; }

    const float* xb = x + (size_t)b * 256 * 1024 + u0 + tx * 8;
#pragma unroll
    for (int i = 0; i < 8; i++) {
        const int t = ty * 8 + i;
        float xv[8];
        *(float4*)(xv)     = *(const float4*)(xb + (size_t)t * 1024);
        *(float4*)(xv + 4) = *(const float4*)(xb + (size_t)t * 1024 + 4);
#pragma unroll
        for (int j = 0; j < 8; j++) {
            float e = __expf(acc[i][j] - cm[j]) ;
            // use precise expf to stay bit-close to reference
            e = expf(acc[i][j] - cm[j]);
            dsum[j] += e;
            pm[j] += e * xv[j];
        }
    }
    __syncthreads();  // red reads above complete before overwrite
#pragma unroll
    for (int j = 0; j < 8; j++) {
        red[ty * 64 + tx * 8 + j] = dsum[j];
        red2[ty * 64 + tx * 8 + j] = pm[j];
    }
    __syncthreads();
    if (tid < 64) {
        float dn = 0.f, p = 0.f;
        for (int yy = 0; yy < 32; yy++) { dn += red[yy * 64 + tid]; p += red2[yy * 64 + tid]; }
        m_out[(size_t)(r * 128 + b) * 1024 + u0 + tid] = p / dn;
    }
}

// ---------------- K3: votes_r[128][2048] = m_r[128][1024] @ cw_r[1024][2048] ----------------
// B in [K,N] layout. BM=128, BN=128, BK=16, 256 thr, 8x8. grid=(16,1,8).
__global__ __launch_bounds__(256) void k3_votes(const float* __restrict__ Mb,
                                                const float* __restrict__ CW,
                                                float* __restrict__ V) {
    __shared__ float As[16][132];
    __shared__ float Bs[16][132];
    const int tid = threadIdx.x;
    const int r = blockIdx.z;
    const int n0 = blockIdx.x * 128;
    const float* A = Mb + (size_t)r * 128 * 1024;
    const float* Bm = CW + (size_t)r * 1024 * 2048;
    float* C = V + (size_t)r * 128 * 2048;
    const int ty = tid >> 4, tx = tid & 15;
    const int k4 = (tid & 3) * 4, row = tid >> 2;   // A loader
    const int n4 = (tid & 31) * 4, krow = tid >> 5; // B loader

    float acc[8][8];
#pragma unroll
    for (int i = 0; i < 8; i++)
#pragma unroll
        for (int j = 0; j < 8; j++) acc[i][j] = 0.f;

    for (int k0 = 0; k0 < 1024; k0 += 16) {
#pragma unroll
        for (int rr = 0; rr < 2; rr++) {
            const int m = row + rr * 64;
            float4 av = *(const float4*)(A + (size_t)m * 1024 + k0 + k4);
            As[k4 + 0][m] = av.x; As[k4 + 1][m] = av.y;
            As[k4 + 2][m] = av.z; As[k4 + 3][m] = av.w;
            const int k = krow + rr * 8;
            float4 bv = *(const float4*)(Bm + (size_t)(k0 + k) * 2048 + n0 + n4);
            *(float4*)(&Bs[k][n4]) = bv;
        }
        __syncthreads();
#pragma unroll
        for (int k = 0; k < 16; k++) {
            float a[8], b[8];
            *(float4*)(a)     = *(const float4*)(&As[k][ty * 8]);
            *(float4*)(a + 4) = *(const float4*)(&As[k][ty * 8 + 4]);
            *(float4*)(b)     = *(const float4*)(&Bs[k][tx * 8]);
            *(float4*)(b + 4) = *(const float4*)(&Bs[k][tx * 8 + 4]);
#pragma unroll
            for (int i = 0; i < 8; i++)
#pragma unroll
                for (int j = 0; j < 8; j++) acc[i][j] += a[i] * b[j];
        }
        __syncthreads();
    }
#pragma unroll
    for (int i = 0; i < 8; i++) {
        const int m = ty * 8 + i;
#pragma unroll
        for (int j = 0; j < 8; j += 4) {
            float4 v;
            v.x = acc[i][j + 0]; v.y = acc[i][j + 1];
            v.z = acc[i][j + 2]; v.w = acc[i][j + 3];
            *(float4*)(C + (size_t)m * 2048 + n0 + tx * 8 + j) = v;
        }
    }
}

// ---------------- K4: dynamic routing, one block per b ----------------
// votes layout: V[(r*128+b)*2048 + c*16 + o]
__global__ __launch_bounds__(256) void k4_routing(const float* __restrict__ V,
                                                  float* __restrict__ out) {
    __shared__ float logits[8 * 128];
    __shared__ float route[8 * 128];
    __shared__ float preact[128 * 16];
    __shared__ float act[128 * 16];
    __shared__ float fred[128];
    const int b = blockIdx.x, tid = threadIdx.x;
    const float* vb = V + (size_t)b * 2048;  // + r*128*2048 per head

    for (int i = tid; i < 1024; i += 256) logits[i] = 0.f;
    __syncthreads();

    for (int it = 0; it < 3; it++) {
        // route = softmax over c of logits[r,:]; 32 lanes per r
        {
            const int r = tid >> 5, g = tid & 31;
            float l[4];
#pragma unroll
            for (int q = 0; q < 4; q++) l[q] = logits[r * 128 + g + q * 32];
            float mx = fmaxf(fmaxf(l[0], l[1]), fmaxf(l[2], l[3]));
            for (int msk = 16; msk; msk >>= 1) mx = fmaxf(mx, __shfl_xor(mx, msk, 32));
            float e[4], s = 0.f;
#pragma unroll
            for (int q = 0; q < 4; q++) { e[q] = expf(l[q] - mx); s += e[q]; }
            for (int msk = 16; msk; msk >>= 1) s += __shfl_xor(s, msk, 32);
            float inv = 1.f / s;
#pragma unroll
            for (int q = 0; q < 4; q++) route[r * 128 + g + q * 32] = e[q] * inv;
        }
        __syncthreads();
        // preact[c][o] = sum_r route[r][c] * votes[r][c][o]
        for (int i = tid; i < 2048; i += 256) {
            const int c = i >> 4;
            float a = 0.f;
#pragma unroll
            for (int r = 0; r < 8; r++)
                a += route[r * 128 + c] * vb[(size_t)r * 128 * 2048 + i];
            preact[i] = a;
        }
        __syncthreads();
        // squash factor per c: f = norm/(1+norm^2)
        if (tid < 128) {
            float n2 = 0.f;
#pragma unroll
            for (int o = 0; o < 16; o++) { float p = preact[tid * 16 + o]; n2 += p * p; }
            fred[tid] = sqrtf(n2) / (1.f + n2);
        }
        __syncthreads();
        for (int i = tid; i < 2048; i += 256) act[i] = preact[i] * fred[i >> 4];
        __syncthreads();
        // logits += dist ; dist[r][c] = sum_o votes[r][c][o]*act[c][o]
        for (int i = tid; i < 1024; i += 256) {
            const int r = i >> 7, c = i & 127;
            float d = 0.f;
#pragma unroll
            for (int o = 0; o < 16; o++)
                d += vb[(size_t)r * 128 * 2048 + c * 16 + o] * act[c * 16 + o];
            logits[i] += d;
        }
        __syncthreads();
    }
    if (tid < 128) {
        float n2 = 0.f;
#pragma unroll
        for (int o = 0; o < 16; o++) { float a = act[tid * 16 + o]; n2 += a * a; }
        out[(size_t)b * 128 + tid] = sqrtf(n2);
    }
}

extern "C" void kernel_launch(void* const* d_in, const int* in_sizes, int n_in,
                              void* d_out, int out_size, void* d_ws, size_t ws_size,
                              hipStream_t stream) {
    const float* x   = (const float*)d_in[0];
    const float* WS1 = (const float*)d_in[1];
    const float* WS2 = (const float*)d_in[2];
    const float* cw  = (const float*)d_in[3];
    float* out = (float*)d_out;

    char* ws = (char*)d_ws;
    float* m_buf = (float*)ws;                        // 8*128*1024 fp32 = 4 MB
    float* votes = (float*)(ws + ((size_t)4 << 20));  // 8*128*2048 fp32 = 8 MB
    float* hbar  = (float*)(ws + ((size_t)16 << 20)); // b-chunked hbar

    const size_t per_b = (size_t)256 * 512 * 4;       // 512 KB per batch row
    int CB = 128;
    {
        size_t base = (size_t)16 << 20;
        if (ws_size < base + 128 * per_b) {
            size_t avail = (ws_size > base) ? (ws_size - base) : per_b;
            CB = (int)(avail / per_b);
            if (CB < 1) CB = 1;
            if (CB > 128) CB = 128;
        }
    }

    for (int r = 0; r < 8; r++) {
        for (int b0 = 0; b0 < 128; b0 += CB) {
            const int bc = (128 - b0 < CB) ? (128 - b0) : CB;
            dim3 g1(4, bc * 2);  // N=512/128 tiles, M=bc*256/128 tiles
            hipLaunchKernelGGL(k1_hbar, g1, dim3(256), 0, stream,
                               x + (size_t)b0 * 256 * 1024,
                               WS1 + (size_t)r * 512 * 1024,
                               hbar);
            dim3 g2(16, bc);     // 16 u-blocks of 64
            hipLaunchKernelGGL(k2_scores_m, g2, dim3(256), 0, stream,
                               hbar,
                               WS2 + (size_t)r * 1024 * 512,
                               x, m_buf, b0, r);
        }
    }
    hipLaunchKernelGGL(k3_votes, dim3(16, 1, 8), dim3(256), 0, stream,
                       m_buf, cw, votes);
    hipLaunchKernelGGL(k4_routing, dim3(128), dim3(256), 0, stream,
                       votes, out);
}

// Round 2
// 2831.714 us; speedup vs baseline: 2.3773x; 2.3773x over previous
//
#include <hip/hip_runtime.h>

// CapsAll on MI355X — split-bf16 MFMA version.
// fp32 operand f = hi + lo (two RNE bf16); GEMM = 3 MFMA passes (hh, hl, lh),
// fp32 accumulate in AGPRs. Relative error ~2^-17, far below the harness
// threshold. K1/K2 move from fp32 VALU (157 TF ceiling) to the matrix pipe
// (2495/3 ~ 830 TF effective ceiling).
//
//   k0: split WS1/WS2 fp32 -> (hi,lo) bf16 planes in ws
//   k1: hbar = relu(x @ WS1_r^T)  [M=bc*256 x 512], x split on-the-fly,
//       output stored as split bf16 planes
//   k2: scores = hbar @ WS2_r^T held in regs (256x64 tile = full T),
//       fused column-softmax over t + m = (sum e*x)/(sum e)   -> m fp32
//   k3: votes = m @ cw (fp32 VALU, only 4.3 GFLOP)
//   k4: dynamic routing (3 iters) + norms
//
// ws: m 4M | votes 8M @4M | W1h/W1l/W2h/W2l 8M each @12..44M | hbar split @44M

typedef __attribute__((ext_vector_type(8))) short bf16x8;
typedef __attribute__((ext_vector_type(8))) unsigned short u16x8;
typedef __attribute__((ext_vector_type(4))) float f32x4;

#define LDT 40  // LDS row stride in bf16 units for 32-wide K tiles (80 B)

__device__ __forceinline__ unsigned short f2bf(float f) {
    unsigned u = __float_as_uint(f);
    u += 0x7FFF + ((u >> 16) & 1);           // round-to-nearest-even
    return (unsigned short)(u >> 16);
}
__device__ __forceinline__ float bf2f(unsigned short h) {
    return __uint_as_float(((unsigned)h) << 16);
}

// ---------------- k0: elementwise fp32 -> (hi,lo) bf16 split ----------------
__global__ __launch_bounds__(256) void k0_split(const float* __restrict__ src,
                                                unsigned short* __restrict__ hi,
                                                unsigned short* __restrict__ lo,
                                                int n4) {
    int i = blockIdx.x * 256 + threadIdx.x;
    if (i >= n4) return;
    float4 v = ((const float4*)src)[i];
    ushort4 h, l;
    h.x = f2bf(v.x); l.x = f2bf(v.x - bf2f(h.x));
    h.y = f2bf(v.y); l.y = f2bf(v.y - bf2f(h.y));
    h.z = f2bf(v.z); l.z = f2bf(v.z - bf2f(h.z));
    h.w = f2bf(v.w); l.w = f2bf(v.w - bf2f(h.w));
    ((ushort4*)hi)[i] = h;
    ((ushort4*)lo)[i] = l;
}

// ---------------- k1: hbar = relu(x @ W1^T), split-bf16 MFMA ----------------
// X fp32 [M x 1024]; W1h/W1l bf16 [512 x 1024]; out Hh/Hl bf16 [M x 512].
// 128x128 tile, BK=32, 256 thr = 4 waves (2x2 of 64x64), 16x16x32 bf16 MFMA.
__global__ __launch_bounds__(256) void k1_hbar_mfma(
    const float* __restrict__ X,
    const unsigned short* __restrict__ Wh,
    const unsigned short* __restrict__ Wl,
    unsigned short* __restrict__ Hh,
    unsigned short* __restrict__ Hl) {
    __shared__ unsigned short Ah[128 * LDT], Al[128 * LDT];
    __shared__ unsigned short Bh[128 * LDT], Bl[128 * LDT];
    const int tid = threadIdx.x;
    const int m0 = blockIdx.y * 128, n0 = blockIdx.x * 128;
    const int wave = tid >> 6, lane = tid & 63;
    const int wm = (wave >> 1) * 64, wn = (wave & 1) * 64;
    const int lx = lane & 15, qd = lane >> 4;
    const int srow = tid >> 1, scol = (tid & 1) * 16;

    f32x4 acc[4][4];
#pragma unroll
    for (int i = 0; i < 4; i++)
#pragma unroll
        for (int j = 0; j < 4; j++) acc[i][j] = (f32x4){0.f, 0.f, 0.f, 0.f};

    const float* xrow = X + (size_t)(m0 + srow) * 1024 + scol;
    const unsigned short* whrow = Wh + (size_t)(n0 + srow) * 1024 + scol;
    const unsigned short* wlrow = Wl + (size_t)(n0 + srow) * 1024 + scol;
    unsigned short* ah = &Ah[srow * LDT + scol];
    unsigned short* al = &Al[srow * LDT + scol];
    unsigned short* bh = &Bh[srow * LDT + scol];
    unsigned short* bl = &Bl[srow * LDT + scol];

    for (int k0 = 0; k0 < 1024; k0 += 32) {
        // A: x fp32 -> hi/lo split into LDS
        float4 v0 = *(const float4*)(xrow + k0);
        float4 v1 = *(const float4*)(xrow + k0 + 4);
        float4 v2 = *(const float4*)(xrow + k0 + 8);
        float4 v3 = *(const float4*)(xrow + k0 + 12);
        float vv[16] = {v0.x, v0.y, v0.z, v0.w, v1.x, v1.y, v1.z, v1.w,
                        v2.x, v2.y, v2.z, v2.w, v3.x, v3.y, v3.z, v3.w};
        u16x8 ph0, ph1, pl0, pl1;
#pragma unroll
        for (int e = 0; e < 8; e++) {
            unsigned short h = f2bf(vv[e]);
            ph0[e] = h; pl0[e] = f2bf(vv[e] - bf2f(h));
        }
#pragma unroll
        for (int e = 0; e < 8; e++) {
            unsigned short h = f2bf(vv[8 + e]);
            ph1[e] = h; pl1[e] = f2bf(vv[8 + e] - bf2f(h));
        }
        *(u16x8*)(ah) = ph0; *(u16x8*)(ah + 8) = ph1;
        *(u16x8*)(al) = pl0; *(u16x8*)(al + 8) = pl1;
        // B: pre-split W1 planes, straight copy
        u16x8 b0 = *(const u16x8*)(whrow + k0);
        u16x8 b1 = *(const u16x8*)(whrow + k0 + 8);
        u16x8 b2 = *(const u16x8*)(wlrow + k0);
        u16x8 b3 = *(const u16x8*)(wlrow + k0 + 8);
        *(u16x8*)(bh) = b0; *(u16x8*)(bh + 8) = b1;
        *(u16x8*)(bl) = b2; *(u16x8*)(bl + 8) = b3;
        __syncthreads();

        bf16x8 fa_h[4], fa_l[4], fb_h[4], fb_l[4];
#pragma unroll
        for (int i = 0; i < 4; i++) {
            const int ar = wm + 16 * i + lx;
            fa_h[i] = *(const bf16x8*)&Ah[ar * LDT + 8 * qd];
            fa_l[i] = *(const bf16x8*)&Al[ar * LDT + 8 * qd];
            const int br = wn + 16 * i + lx;
            fb_h[i] = *(const bf16x8*)&Bh[br * LDT + 8 * qd];
            fb_l[i] = *(const bf16x8*)&Bl[br * LDT + 8 * qd];
        }
#pragma unroll
        for (int i = 0; i < 4; i++)
#pragma unroll
            for (int j = 0; j < 4; j++)
                acc[i][j] = __builtin_amdgcn_mfma_f32_16x16x32_bf16(fa_h[i], fb_h[j], acc[i][j], 0, 0, 0);
#pragma unroll
        for (int i = 0; i < 4; i++)
#pragma unroll
            for (int j = 0; j < 4; j++)
                acc[i][j] = __builtin_amdgcn_mfma_f32_16x16x32_bf16(fa_h[i], fb_l[j], acc[i][j], 0, 0, 0);
#pragma unroll
        for (int i = 0; i < 4; i++)
#pragma unroll
            for (int j = 0; j < 4; j++)
                acc[i][j] = __builtin_amdgcn_mfma_f32_16x16x32_bf16(fa_l[i], fb_h[j], acc[i][j], 0, 0, 0);
        __syncthreads();
    }

    // epilogue: relu, split to hi/lo bf16, store
#pragma unroll
    for (int i = 0; i < 4; i++)
#pragma unroll
        for (int j = 0; j < 4; j++) {
            const int col = n0 + wn + 16 * j + lx;
#pragma unroll
            for (int p = 0; p < 4; p++) {
                const int row = m0 + wm + 16 * i + 4 * qd + p;
                float v = fmaxf(acc[i][j][p], 0.f);
                unsigned short h = f2bf(v);
                unsigned short l = f2bf(v - bf2f(h));
                Hh[(size_t)row * 512 + col] = h;
                Hl[(size_t)row * 512 + col] = l;
            }
        }
}

// ------- k2: scores (256x64 reg tile) + column softmax over t + m -------
// A = hbar split [256 x 512]; B = W2 split [1024 x 512]; K=512.
// 4 waves stacked on M (64 rows each), 4x4 frags per wave.
__global__ __launch_bounds__(256) void k2_mfma(
    const unsigned short* __restrict__ Hh, const unsigned short* __restrict__ Hl,
    const unsigned short* __restrict__ W2h, const unsigned short* __restrict__ W2l,
    const float* __restrict__ x, float* __restrict__ m_out, int b0, int r) {
    __shared__ unsigned short Ah[256 * LDT], Al[256 * LDT];
    __shared__ unsigned short Bh[64 * LDT], Bl[64 * LDT];
    __shared__ float mred[4 * 64], sred[4 * 64], pred[4 * 64];
    const int tid = threadIdx.x;
    const int b_local = blockIdx.y, b = b0 + b_local;
    const int u0 = blockIdx.x * 64;
    const int wave = tid >> 6, lane = tid & 63;
    const int lx = lane & 15, qd = lane >> 4;

    const unsigned short* ahrow = Hh + (size_t)(b_local * 256 + tid) * 512;
    const unsigned short* alrow = Hl + (size_t)(b_local * 256 + tid) * 512;
    const int brow = tid >> 2, bcol = (tid & 3) * 8;
    const unsigned short* bhrow = W2h + (size_t)(u0 + brow) * 512 + bcol;
    const unsigned short* blrow = W2l + (size_t)(u0 + brow) * 512 + bcol;

    f32x4 acc[4][4];
#pragma unroll
    for (int i = 0; i < 4; i++)
#pragma unroll
        for (int j = 0; j < 4; j++) acc[i][j] = (f32x4){0.f, 0.f, 0.f, 0.f};

    for (int k0 = 0; k0 < 512; k0 += 32) {
        u16x8 a0 = *(const u16x8*)(ahrow + k0);
        u16x8 a1 = *(const u16x8*)(ahrow + k0 + 8);
        u16x8 a2 = *(const u16x8*)(ahrow + k0 + 16);
        u16x8 a3 = *(const u16x8*)(ahrow + k0 + 24);
        *(u16x8*)&Ah[tid * LDT + 0] = a0;  *(u16x8*)&Ah[tid * LDT + 8] = a1;
        *(u16x8*)&Ah[tid * LDT + 16] = a2; *(u16x8*)&Ah[tid * LDT + 24] = a3;
        u16x8 a4 = *(const u16x8*)(alrow + k0);
        u16x8 a5 = *(const u16x8*)(alrow + k0 + 8);
        u16x8 a6 = *(const u16x8*)(alrow + k0 + 16);
        u16x8 a7 = *(const u16x8*)(alrow + k0 + 24);
        *(u16x8*)&Al[tid * LDT + 0] = a4;  *(u16x8*)&Al[tid * LDT + 8] = a5;
        *(u16x8*)&Al[tid * LDT + 16] = a6; *(u16x8*)&Al[tid * LDT + 24] = a7;
        u16x8 bhv = *(const u16x8*)(bhrow + k0);
        u16x8 blv = *(const u16x8*)(blrow + k0);
        *(u16x8*)&Bh[brow * LDT + bcol] = bhv;
        *(u16x8*)&Bl[brow * LDT + bcol] = blv;
        __syncthreads();

        bf16x8 fa_h[4], fa_l[4], fb_h[4], fb_l[4];
#pragma unroll
        for (int i = 0; i < 4; i++) {
            const int ar = 64 * wave + 16 * i + lx;
            fa_h[i] = *(const bf16x8*)&Ah[ar * LDT + 8 * qd];
            fa_l[i] = *(const bf16x8*)&Al[ar * LDT + 8 * qd];
            const int br = 16 * i + lx;
            fb_h[i] = *(const bf16x8*)&Bh[br * LDT + 8 * qd];
            fb_l[i] = *(const bf16x8*)&Bl[br * LDT + 8 * qd];
        }
#pragma unroll
        for (int i = 0; i < 4; i++)
#pragma unroll
            for (int j = 0; j < 4; j++)
                acc[i][j] = __builtin_amdgcn_mfma_f32_16x16x32_bf16(fa_h[i], fb_h[j], acc[i][j], 0, 0, 0);
#pragma unroll
        for (int i = 0; i < 4; i++)
#pragma unroll
            for (int j = 0; j < 4; j++)
                acc[i][j] = __builtin_amdgcn_mfma_f32_16x16x32_bf16(fa_h[i], fb_l[j], acc[i][j], 0, 0, 0);
#pragma unroll
        for (int i = 0; i < 4; i++)
#pragma unroll
            for (int j = 0; j < 4; j++)
                acc[i][j] = __builtin_amdgcn_mfma_f32_16x16x32_bf16(fa_l[i], fb_h[j], acc[i][j], 0, 0, 0);
        __syncthreads();
    }

    // ---- column max over t (rows): per-lane -> cross-quad -> cross-wave ----
    float cm[4];
#pragma unroll
    for (int j = 0; j < 4; j++) {
        float mx = acc[0][j][0];
#pragma unroll
        for (int i = 0; i < 4; i++)
#pragma unroll
            for (int p = 0; p < 4; p++) mx = fmaxf(mx, acc[i][j][p]);
        mx = fmaxf(mx, __shfl_xor(mx, 16, 64));
        mx = fmaxf(mx, __shfl_xor(mx, 32, 64));
        if (qd == 0) mred[wave * 64 + 16 * j + lx] = mx;
    }
    __syncthreads();
#pragma unroll
    for (int j = 0; j < 4; j++) {
        const int c = 16 * j + lx;
        cm[j] = fmaxf(fmaxf(mred[c], mred[64 + c]), fmaxf(mred[128 + c], mred[192 + c]));
    }

    // ---- exp + weighted sum against x ----
    float ds[4] = {0.f, 0.f, 0.f, 0.f}, pm[4] = {0.f, 0.f, 0.f, 0.f};
    const float* xb = x + (size_t)b * 256 * 1024 + u0;
#pragma unroll
    for (int i = 0; i < 4; i++) {
#pragma unroll
        for (int p = 0; p < 4; p++) {
            const int t = 64 * wave + 16 * i + 4 * qd + p;
            const float* xr = xb + (size_t)t * 1024;
            float xv[4];
#pragma unroll
            for (int j = 0; j < 4; j++) xv[j] = xr[16 * j + lx];
#pragma unroll
            for (int j = 0; j < 4; j++) {
                float e = expf(acc[i][j][p] - cm[j]);
                ds[j] += e;
                pm[j] += e * xv[j];
            }
        }
    }
#pragma unroll
    for (int j = 0; j < 4; j++) {
        ds[j] += __shfl_xor(ds[j], 16, 64);
        ds[j] += __shfl_xor(ds[j], 32, 64);
        pm[j] += __shfl_xor(pm[j], 16, 64);
        pm[j] += __shfl_xor(pm[j], 32, 64);
        if (qd == 0) {
            sred[wave * 64 + 16 * j + lx] = ds[j];
            pred[wave * 64 + 16 * j + lx] = pm[j];
        }
    }
    __syncthreads();
    if (tid < 64) {
        float dsum = sred[tid] + sred[64 + tid] + sred[128 + tid] + sred[192 + tid];
        float psum = pred[tid] + pred[64 + tid] + pred[128 + tid] + pred[192 + tid];
        m_out[(size_t)(r * 128 + b) * 1024 + u0 + tid] = psum / dsum;
    }
}

// ---------------- k3: votes = m @ cw (fp32 VALU, unchanged) ----------------
__global__ __launch_bounds__(256) void k3_votes(const float* __restrict__ Mb,
                                                const float* __restrict__ CW,
                                                float* __restrict__ V) {
    __shared__ float As[16][132];
    __shared__ float Bs[16][132];
    const int tid = threadIdx.x;
    const int r = blockIdx.z;
    const int n0 = blockIdx.x * 128;
    const float* A = Mb + (size_t)r * 128 * 1024;
    const float* Bm = CW + (size_t)r * 1024 * 2048;
    float* C = V + (size_t)r * 128 * 2048;
    const int ty = tid >> 4, tx = tid & 15;
    const int k4 = (tid & 3) * 4, row = tid >> 2;
    const int n4 = (tid & 31) * 4, krow = tid >> 5;

    float acc[8][8];
#pragma unroll
    for (int i = 0; i < 8; i++)
#pragma unroll
        for (int j = 0; j < 8; j++) acc[i][j] = 0.f;

    for (int k0 = 0; k0 < 1024; k0 += 16) {
#pragma unroll
        for (int rr = 0; rr < 2; rr++) {
            const int m = row + rr * 64;
            float4 av = *(const float4*)(A + (size_t)m * 1024 + k0 + k4);
            As[k4 + 0][m] = av.x; As[k4 + 1][m] = av.y;
            As[k4 + 2][m] = av.z; As[k4 + 3][m] = av.w;
            const int k = krow + rr * 8;
            float4 bv = *(const float4*)(Bm + (size_t)(k0 + k) * 2048 + n0 + n4);
            *(float4*)(&Bs[k][n4]) = bv;
        }
        __syncthreads();
#pragma unroll
        for (int k = 0; k < 16; k++) {
            float a[8], b[8];
            *(float4*)(a)     = *(const float4*)(&As[k][ty * 8]);
            *(float4*)(a + 4) = *(const float4*)(&As[k][ty * 8 + 4]);
            *(float4*)(b)     = *(const float4*)(&Bs[k][tx * 8]);
            *(float4*)(b + 4) = *(const float4*)(&Bs[k][tx * 8 + 4]);
#pragma unroll
            for (int i = 0; i < 8; i++)
#pragma unroll
                for (int j = 0; j < 8; j++) acc[i][j] += a[i] * b[j];
        }
        __syncthreads();
    }
#pragma unroll
    for (int i = 0; i < 8; i++) {
        const int m = ty * 8 + i;
#pragma unroll
        for (int j = 0; j < 8; j += 4) {
            float4 v;
            v.x = acc[i][j + 0]; v.y = acc[i][j + 1];
            v.z = acc[i][j + 2]; v.w = acc[i][j + 3];
            *(float4*)(C + (size_t)m * 2048 + n0 + tx * 8 + j) = v;
        }
    }
}

// ---------------- k4: dynamic routing (unchanged) ----------------
__global__ __launch_bounds__(256) void k4_routing(const float* __restrict__ V,
                                                  float* __restrict__ out) {
    __shared__ float logits[8 * 128];
    __shared__ float route[8 * 128];
    __shared__ float preact[128 * 16];
    __shared__ float act[128 * 16];
    __shared__ float fred[128];
    const int b = blockIdx.x, tid = threadIdx.x;
    const float* vb = V + (size_t)b * 2048;

    for (int i = tid; i < 1024; i += 256) logits[i] = 0.f;
    __syncthreads();

    for (int it = 0; it < 3; it++) {
        {
            const int r = tid >> 5, g = tid & 31;
            float l[4];
#pragma unroll
            for (int q = 0; q < 4; q++) l[q] = logits[r * 128 + g + q * 32];
            float mx = fmaxf(fmaxf(l[0], l[1]), fmaxf(l[2], l[3]));
            for (int msk = 16; msk; msk >>= 1) mx = fmaxf(mx, __shfl_xor(mx, msk, 32));
            float e[4], s = 0.f;
#pragma unroll
            for (int q = 0; q < 4; q++) { e[q] = expf(l[q] - mx); s += e[q]; }
            for (int msk = 16; msk; msk >>= 1) s += __shfl_xor(s, msk, 32);
            float inv = 1.f / s;
#pragma unroll
            for (int q = 0; q < 4; q++) route[r * 128 + g + q * 32] = e[q] * inv;
        }
        __syncthreads();
        for (int i = tid; i < 2048; i += 256) {
            const int c = i >> 4;
            float a = 0.f;
#pragma unroll
            for (int r = 0; r < 8; r++)
                a += route[r * 128 + c] * vb[(size_t)r * 128 * 2048 + i];
            preact[i] = a;
        }
        __syncthreads();
        if (tid < 128) {
            float n2 = 0.f;
#pragma unroll
            for (int o = 0; o < 16; o++) { float p = preact[tid * 16 + o]; n2 += p * p; }
            fred[tid] = sqrtf(n2) / (1.f + n2);
        }
        __syncthreads();
        for (int i = tid; i < 2048; i += 256) act[i] = preact[i] * fred[i >> 4];
        __syncthreads();
        for (int i = tid; i < 1024; i += 256) {
            const int r = i >> 7, c = i & 127;
            float d = 0.f;
#pragma unroll
            for (int o = 0; o < 16; o++)
                d += vb[(size_t)r * 128 * 2048 + c * 16 + o] * act[c * 16 + o];
            logits[i] += d;
        }
        __syncthreads();
    }
    if (tid < 128) {
        float n2 = 0.f;
#pragma unroll
        for (int o = 0; o < 16; o++) { float a = act[tid * 16 + o]; n2 += a * a; }
        out[(size_t)b * 128 + tid] = sqrtf(n2);
    }
}

extern "C" void kernel_launch(void* const* d_in, const int* in_sizes, int n_in,
                              void* d_out, int out_size, void* d_ws, size_t ws_size,
                              hipStream_t stream) {
    const float* x   = (const float*)d_in[0];
    const float* WS1 = (const float*)d_in[1];
    const float* WS2 = (const float*)d_in[2];
    const float* cw  = (const float*)d_in[3];
    float* out = (float*)d_out;

    char* ws = (char*)d_ws;
    float* m_buf = (float*)ws;                                  // 4 MiB
    float* votes = (float*)(ws + ((size_t)4 << 20));            // 8 MiB
    unsigned short* W1h = (unsigned short*)(ws + ((size_t)12 << 20));
    unsigned short* W1l = (unsigned short*)(ws + ((size_t)20 << 20));
    unsigned short* W2h = (unsigned short*)(ws + ((size_t)28 << 20));
    unsigned short* W2l = (unsigned short*)(ws + ((size_t)36 << 20));

    const size_t fixed = (size_t)44 << 20;
    const size_t perb  = (size_t)512 << 10;   // hbar hi+lo per batch row
    int CB = 128;
    if (ws_size < fixed + 128 * perb) {
        size_t avail = (ws_size > fixed) ? (ws_size - fixed) : perb;
        CB = (int)(avail / perb);
        if (CB < 1) CB = 1;
        if (CB > 128) CB = 128;
    }
    unsigned short* Hh = (unsigned short*)(ws + fixed);
    unsigned short* Hl = Hh + (size_t)CB * 256 * 512;

    const int n4 = (8 * 512 * 1024) / 4;      // same count for WS1 and WS2
    hipLaunchKernelGGL(k0_split, dim3((n4 + 255) / 256), dim3(256), 0, stream,
                       WS1, W1h, W1l, n4);
    hipLaunchKernelGGL(k0_split, dim3((n4 + 255) / 256), dim3(256), 0, stream,
                       WS2, W2h, W2l, n4);

    for (int b0 = 0; b0 < 128; b0 += CB) {
        const int bc = (128 - b0 < CB) ? (128 - b0) : CB;
        for (int r = 0; r < 8; r++) {
            hipLaunchKernelGGL(k1_hbar_mfma, dim3(4, bc * 2), dim3(256), 0, stream,
                               x + (size_t)b0 * 256 * 1024,
                               W1h + (size_t)r * 512 * 1024,
                               W1l + (size_t)r * 512 * 1024,
                               Hh, Hl);
            hipLaunchKernelGGL(k2_mfma, dim3(16, bc), dim3(256), 0, stream,
                               Hh, Hl,
                               W2h + (size_t)r * 1024 * 512,
                               W2l + (size_t)r * 1024 * 512,
                               x, m_buf, b0, r);
        }
    }
    hipLaunchKernelGGL(k3_votes, dim3(16, 1, 8), dim3(256), 0, stream,
                       m_buf, cw, votes);
    hipLaunchKernelGGL(k4_routing, dim3(128), dim3(256), 0, stream,
                       votes, out);
}

// Round 3
// 2179.122 us; speedup vs baseline: 3.0892x; 1.2995x over previous
//
#include <hip/hip_runtime.h>

// CapsAll on MI355X — split-bf16 MFMA, round 3.
// Weights are split fp32 = hi + lo (two RNE bf16); activations (x, hbar) are
// bf16-hi ONLY (error budget: ~1e-3 relative on scores, ~4e-7 absolute on the
// final output vs 1.9e-6 threshold). Each GEMM tile = 2 MFMA passes:
// A_hi x B_hi + A_hi x B_lo, fp32 accumulate.
//
//   k0: split WS1/WS2 fp32 -> (hi,lo) bf16 planes in ws
//   k1: hbar = relu(x @ WS1_r^T), x converted to bf16-hi on the fly,
//       output stored as ONE bf16 plane (Hh)
//   k2: scores = Hh @ WS2_r^T (256x64 reg tile = full T),
//       fused column-softmax over t + m = (sum e*x)/(sum e)
//   k3: votes = m @ cw (fp32 VALU, 4.3 GFLOP)
//   k4: dynamic routing (3 iters) + norms
//
// ws: m 4M | votes 8M @4M | W1h/W1l/W2h/W2l 8M each @12..44M | Hh @44M (32M)

typedef __attribute__((ext_vector_type(8))) short bf16x8;
typedef __attribute__((ext_vector_type(8))) unsigned short u16x8;
typedef __attribute__((ext_vector_type(4))) float f32x4;

#define LDT 40  // LDS row stride in bf16 (80 B): 16B-aligned b128, 2-way banks

__device__ __forceinline__ unsigned short f2bf(float f) {
    unsigned u = __float_as_uint(f);
    u += 0x7FFF + ((u >> 16) & 1);           // round-to-nearest-even
    return (unsigned short)(u >> 16);
}
__device__ __forceinline__ float bf2f(unsigned short h) {
    return __uint_as_float(((unsigned)h) << 16);
}

// ---------------- k0: elementwise fp32 -> (hi,lo) bf16 split ----------------
__global__ __launch_bounds__(256) void k0_split(const float* __restrict__ src,
                                                unsigned short* __restrict__ hi,
                                                unsigned short* __restrict__ lo,
                                                int n4) {
    int i = blockIdx.x * 256 + threadIdx.x;
    if (i >= n4) return;
    float4 v = ((const float4*)src)[i];
    ushort4 h, l;
    h.x = f2bf(v.x); l.x = f2bf(v.x - bf2f(h.x));
    h.y = f2bf(v.y); l.y = f2bf(v.y - bf2f(h.y));
    h.z = f2bf(v.z); l.z = f2bf(v.z - bf2f(h.z));
    h.w = f2bf(v.w); l.w = f2bf(v.w - bf2f(h.w));
    ((ushort4*)hi)[i] = h;
    ((ushort4*)lo)[i] = l;
}

// ---------------- k1: hbar = relu(x @ W1^T) ----------------
// X fp32 [M x 1024] -> bf16-hi inline; W1h/W1l bf16 [512 x 1024];
// out Hh bf16 [M x 512]. 128x128 tile, BK=32, 4 waves (2x2 of 64x64).
__global__ __launch_bounds__(256) void k1_hbar_mfma(
    const float* __restrict__ X,
    const unsigned short* __restrict__ Wh,
    const unsigned short* __restrict__ Wl,
    unsigned short* __restrict__ Hh) {
    __shared__ unsigned short Ah[128 * LDT];
    __shared__ unsigned short Bh[128 * LDT], Bl[128 * LDT];
    const int tid = threadIdx.x;
    const int m0 = blockIdx.y * 128, n0 = blockIdx.x * 128;
    const int wave = tid >> 6, lane = tid & 63;
    const int wm = (wave >> 1) * 64, wn = (wave & 1) * 64;
    const int lx = lane & 15, qd = lane >> 4;
    const int srow = tid >> 1, scol = (tid & 1) * 16;

    f32x4 acc[4][4];
#pragma unroll
    for (int i = 0; i < 4; i++)
#pragma unroll
        for (int j = 0; j < 4; j++) acc[i][j] = (f32x4){0.f, 0.f, 0.f, 0.f};

    const float* xrow = X + (size_t)(m0 + srow) * 1024 + scol;
    const unsigned short* whrow = Wh + (size_t)(n0 + srow) * 1024 + scol;
    const unsigned short* wlrow = Wl + (size_t)(n0 + srow) * 1024 + scol;
    unsigned short* ah = &Ah[srow * LDT + scol];
    unsigned short* bh = &Bh[srow * LDT + scol];
    unsigned short* bl = &Bl[srow * LDT + scol];

    for (int k0 = 0; k0 < 1024; k0 += 32) {
        // A: x fp32 -> bf16 hi only
        float4 v0 = *(const float4*)(xrow + k0);
        float4 v1 = *(const float4*)(xrow + k0 + 4);
        float4 v2 = *(const float4*)(xrow + k0 + 8);
        float4 v3 = *(const float4*)(xrow + k0 + 12);
        float vv[16] = {v0.x, v0.y, v0.z, v0.w, v1.x, v1.y, v1.z, v1.w,
                        v2.x, v2.y, v2.z, v2.w, v3.x, v3.y, v3.z, v3.w};
        u16x8 ph0, ph1;
#pragma unroll
        for (int e = 0; e < 8; e++) ph0[e] = f2bf(vv[e]);
#pragma unroll
        for (int e = 0; e < 8; e++) ph1[e] = f2bf(vv[8 + e]);
        *(u16x8*)(ah) = ph0; *(u16x8*)(ah + 8) = ph1;
        // B: pre-split W1 planes, straight copy
        u16x8 b0 = *(const u16x8*)(whrow + k0);
        u16x8 b1 = *(const u16x8*)(whrow + k0 + 8);
        u16x8 b2 = *(const u16x8*)(wlrow + k0);
        u16x8 b3 = *(const u16x8*)(wlrow + k0 + 8);
        *(u16x8*)(bh) = b0; *(u16x8*)(bh + 8) = b1;
        *(u16x8*)(bl) = b2; *(u16x8*)(bl + 8) = b3;
        __syncthreads();

        bf16x8 fa[4], fb_h[4], fb_l[4];
#pragma unroll
        for (int i = 0; i < 4; i++) {
            fa[i]   = *(const bf16x8*)&Ah[(wm + 16 * i + lx) * LDT + 8 * qd];
            fb_h[i] = *(const bf16x8*)&Bh[(wn + 16 * i + lx) * LDT + 8 * qd];
            fb_l[i] = *(const bf16x8*)&Bl[(wn + 16 * i + lx) * LDT + 8 * qd];
        }
#pragma unroll
        for (int i = 0; i < 4; i++)
#pragma unroll
            for (int j = 0; j < 4; j++)
                acc[i][j] = __builtin_amdgcn_mfma_f32_16x16x32_bf16(fa[i], fb_h[j], acc[i][j], 0, 0, 0);
#pragma unroll
        for (int i = 0; i < 4; i++)
#pragma unroll
            for (int j = 0; j < 4; j++)
                acc[i][j] = __builtin_amdgcn_mfma_f32_16x16x32_bf16(fa[i], fb_l[j], acc[i][j], 0, 0, 0);
        __syncthreads();
    }

    // epilogue: relu, bf16-hi, store
#pragma unroll
    for (int i = 0; i < 4; i++)
#pragma unroll
        for (int j = 0; j < 4; j++) {
            const int col = n0 + wn + 16 * j + lx;
#pragma unroll
            for (int p = 0; p < 4; p++) {
                const int row = m0 + wm + 16 * i + 4 * qd + p;
                Hh[(size_t)row * 512 + col] = f2bf(fmaxf(acc[i][j][p], 0.f));
            }
        }
}

// ------- k2: scores (256x64 reg tile) + column softmax over t + m -------
// A = Hh [256 x 512] (one plane); B = W2 split [1024 x 512]; K=512.
// 4 waves stacked on M (64 rows each), 4x4 frags per wave.
__global__ __launch_bounds__(256) void k2_mfma(
    const unsigned short* __restrict__ Hh,
    const unsigned short* __restrict__ W2h, const unsigned short* __restrict__ W2l,
    const float* __restrict__ x, float* __restrict__ m_out, int b0, int r) {
    __shared__ unsigned short Ah[256 * LDT];
    __shared__ unsigned short Bh[64 * LDT], Bl[64 * LDT];
    __shared__ float mred[4 * 64], sred[4 * 64], pred[4 * 64];
    const int tid = threadIdx.x;
    const int b_local = blockIdx.y, b = b0 + b_local;
    const int u0 = blockIdx.x * 64;
    const int wave = tid >> 6, lane = tid & 63;
    const int lx = lane & 15, qd = lane >> 4;

    const unsigned short* ahrow = Hh + (size_t)(b_local * 256 + tid) * 512;
    const int brow = tid >> 2, bcol = (tid & 3) * 8;
    const unsigned short* bhrow = W2h + (size_t)(u0 + brow) * 512 + bcol;
    const unsigned short* blrow = W2l + (size_t)(u0 + brow) * 512 + bcol;

    f32x4 acc[4][4];
#pragma unroll
    for (int i = 0; i < 4; i++)
#pragma unroll
        for (int j = 0; j < 4; j++) acc[i][j] = (f32x4){0.f, 0.f, 0.f, 0.f};

    for (int k0 = 0; k0 < 512; k0 += 32) {
        u16x8 a0 = *(const u16x8*)(ahrow + k0);
        u16x8 a1 = *(const u16x8*)(ahrow + k0 + 8);
        u16x8 a2 = *(const u16x8*)(ahrow + k0 + 16);
        u16x8 a3 = *(const u16x8*)(ahrow + k0 + 24);
        *(u16x8*)&Ah[tid * LDT + 0] = a0;  *(u16x8*)&Ah[tid * LDT + 8] = a1;
        *(u16x8*)&Ah[tid * LDT + 16] = a2; *(u16x8*)&Ah[tid * LDT + 24] = a3;
        u16x8 bhv = *(const u16x8*)(bhrow + k0);
        u16x8 blv = *(const u16x8*)(blrow + k0);
        *(u16x8*)&Bh[brow * LDT + bcol] = bhv;
        *(u16x8*)&Bl[brow * LDT + bcol] = blv;
        __syncthreads();

        bf16x8 fa[4], fb_h[4], fb_l[4];
#pragma unroll
        for (int i = 0; i < 4; i++) {
            fa[i]   = *(const bf16x8*)&Ah[(64 * wave + 16 * i + lx) * LDT + 8 * qd];
            fb_h[i] = *(const bf16x8*)&Bh[(16 * i + lx) * LDT + 8 * qd];
            fb_l[i] = *(const bf16x8*)&Bl[(16 * i + lx) * LDT + 8 * qd];
        }
#pragma unroll
        for (int i = 0; i < 4; i++)
#pragma unroll
            for (int j = 0; j < 4; j++)
                acc[i][j] = __builtin_amdgcn_mfma_f32_16x16x32_bf16(fa[i], fb_h[j], acc[i][j], 0, 0, 0);
#pragma unroll
        for (int i = 0; i < 4; i++)
#pragma unroll
            for (int j = 0; j < 4; j++)
                acc[i][j] = __builtin_amdgcn_mfma_f32_16x16x32_bf16(fa[i], fb_l[j], acc[i][j], 0, 0, 0);
        __syncthreads();
    }

    // ---- column max over t: per-lane -> cross-quad -> cross-wave ----
    float cm[4];
#pragma unroll
    for (int j = 0; j < 4; j++) {
        float mx = acc[0][j][0];
#pragma unroll
        for (int i = 0; i < 4; i++)
#pragma unroll
            for (int p = 0; p < 4; p++) mx = fmaxf(mx, acc[i][j][p]);
        mx = fmaxf(mx, __shfl_xor(mx, 16, 64));
        mx = fmaxf(mx, __shfl_xor(mx, 32, 64));
        if (qd == 0) mred[wave * 64 + 16 * j + lx] = mx;
    }
    __syncthreads();
#pragma unroll
    for (int j = 0; j < 4; j++) {
        const int c = 16 * j + lx;
        cm[j] = fmaxf(fmaxf(mred[c], mred[64 + c]), fmaxf(mred[128 + c], mred[192 + c]));
    }

    // ---- exp + weighted sum against x ----
    float ds[4] = {0.f, 0.f, 0.f, 0.f}, pm[4] = {0.f, 0.f, 0.f, 0.f};
    const float* xb = x + (size_t)b * 256 * 1024 + u0;
#pragma unroll
    for (int i = 0; i < 4; i++) {
#pragma unroll
        for (int p = 0; p < 4; p++) {
            const int t = 64 * wave + 16 * i + 4 * qd + p;
            const float* xr = xb + (size_t)t * 1024;
            float xv[4];
#pragma unroll
            for (int j = 0; j < 4; j++) xv[j] = xr[16 * j + lx];
#pragma unroll
            for (int j = 0; j < 4; j++) {
                float e = expf(acc[i][j][p] - cm[j]);
                ds[j] += e;
                pm[j] += e * xv[j];
            }
        }
    }
#pragma unroll
    for (int j = 0; j < 4; j++) {
        ds[j] += __shfl_xor(ds[j], 16, 64);
        ds[j] += __shfl_xor(ds[j], 32, 64);
        pm[j] += __shfl_xor(pm[j], 16, 64);
        pm[j] += __shfl_xor(pm[j], 32, 64);
        if (qd == 0) {
            sred[wave * 64 + 16 * j + lx] = ds[j];
            pred[wave * 64 + 16 * j + lx] = pm[j];
        }
    }
    __syncthreads();
    if (tid < 64) {
        float dsum = sred[tid] + sred[64 + tid] + sred[128 + tid] + sred[192 + tid];
        float psum = pred[tid] + pred[64 + tid] + pred[128 + tid] + pred[192 + tid];
        m_out[(size_t)(r * 128 + b) * 1024 + u0 + tid] = psum / dsum;
    }
}

// ---------------- k3: votes = m @ cw (fp32 VALU) ----------------
__global__ __launch_bounds__(256) void k3_votes(const float* __restrict__ Mb,
                                                const float* __restrict__ CW,
                                                float* __restrict__ V) {
    __shared__ float As[16][132];
    __shared__ float Bs[16][132];
    const int tid = threadIdx.x;
    const int r = blockIdx.z;
    const int n0 = blockIdx.x * 128;
    const float* A = Mb + (size_t)r * 128 * 1024;
    const float* Bm = CW + (size_t)r * 1024 * 2048;
    float* C = V + (size_t)r * 128 * 2048;
    const int ty = tid >> 4, tx = tid & 15;
    const int k4 = (tid & 3) * 4, row = tid >> 2;
    const int n4 = (tid & 31) * 4, krow = tid >> 5;

    float acc[8][8];
#pragma unroll
    for (int i = 0; i < 8; i++)
#pragma unroll
        for (int j = 0; j < 8; j++) acc[i][j] = 0.f;

    for (int k0 = 0; k0 < 1024; k0 += 16) {
#pragma unroll
        for (int rr = 0; rr < 2; rr++) {
            const int m = row + rr * 64;
            float4 av = *(const float4*)(A + (size_t)m * 1024 + k0 + k4);
            As[k4 + 0][m] = av.x; As[k4 + 1][m] = av.y;
            As[k4 + 2][m] = av.z; As[k4 + 3][m] = av.w;
            const int k = krow + rr * 8;
            float4 bv = *(const float4*)(Bm + (size_t)(k0 + k) * 2048 + n0 + n4);
            *(float4*)(&Bs[k][n4]) = bv;
        }
        __syncthreads();
#pragma unroll
        for (int k = 0; k < 16; k++) {
            float a[8], b[8];
            *(float4*)(a)     = *(const float4*)(&As[k][ty * 8]);
            *(float4*)(a + 4) = *(const float4*)(&As[k][ty * 8 + 4]);
            *(float4*)(b)     = *(const float4*)(&Bs[k][tx * 8]);
            *(float4*)(b + 4) = *(const float4*)(&Bs[k][tx * 8 + 4]);
#pragma unroll
            for (int i = 0; i < 8; i++)
#pragma unroll
                for (int j = 0; j < 8; j++) acc[i][j] += a[i] * b[j];
        }
        __syncthreads();
    }
#pragma unroll
    for (int i = 0; i < 8; i++) {
        const int m = ty * 8 + i;
#pragma unroll
        for (int j = 0; j < 8; j += 4) {
            float4 v;
            v.x = acc[i][j + 0]; v.y = acc[i][j + 1];
            v.z = acc[i][j + 2]; v.w = acc[i][j + 3];
            *(float4*)(C + (size_t)m * 2048 + n0 + tx * 8 + j) = v;
        }
    }
}

// ---------------- k4: dynamic routing ----------------
__global__ __launch_bounds__(256) void k4_routing(const float* __restrict__ V,
                                                  float* __restrict__ out) {
    __shared__ float logits[8 * 128];
    __shared__ float route[8 * 128];
    __shared__ float preact[128 * 16];
    __shared__ float act[128 * 16];
    __shared__ float fred[128];
    const int b = blockIdx.x, tid = threadIdx.x;
    const float* vb = V + (size_t)b * 2048;

    for (int i = tid; i < 1024; i += 256) logits[i] = 0.f;
    __syncthreads();

    for (int it = 0; it < 3; it++) {
        {
            const int r = tid >> 5, g = tid & 31;
            float l[4];
#pragma unroll
            for (int q = 0; q < 4; q++) l[q] = logits[r * 128 + g + q * 32];
            float mx = fmaxf(fmaxf(l[0], l[1]), fmaxf(l[2], l[3]));
            for (int msk = 16; msk; msk >>= 1) mx = fmaxf(mx, __shfl_xor(mx, msk, 32));
            float e[4], s = 0.f;
#pragma unroll
            for (int q = 0; q < 4; q++) { e[q] = expf(l[q] - mx); s += e[q]; }
            for (int msk = 16; msk; msk >>= 1) s += __shfl_xor(s, msk, 32);
            float inv = 1.f / s;
#pragma unroll
            for (int q = 0; q < 4; q++) route[r * 128 + g + q * 32] = e[q] * inv;
        }
        __syncthreads();
        for (int i = tid; i < 2048; i += 256) {
            const int c = i >> 4;
            float a = 0.f;
#pragma unroll
            for (int r = 0; r < 8; r++)
                a += route[r * 128 + c] * vb[(size_t)r * 128 * 2048 + i];
            preact[i] = a;
        }
        __syncthreads();
        if (tid < 128) {
            float n2 = 0.f;
#pragma unroll
            for (int o = 0; o < 16; o++) { float p = preact[tid * 16 + o]; n2 += p * p; }
            fred[tid] = sqrtf(n2) / (1.f + n2);
        }
        __syncthreads();
        for (int i = tid; i < 2048; i += 256) act[i] = preact[i] * fred[i >> 4];
        __syncthreads();
        for (int i = tid; i < 1024; i += 256) {
            const int r = i >> 7, c = i & 127;
            float d = 0.f;
#pragma unroll
            for (int o = 0; o < 16; o++)
                d += vb[(size_t)r * 128 * 2048 + c * 16 + o] * act[c * 16 + o];
            logits[i] += d;
        }
        __syncthreads();
    }
    if (tid < 128) {
        float n2 = 0.f;
#pragma unroll
        for (int o = 0; o < 16; o++) { float a = act[tid * 16 + o]; n2 += a * a; }
        out[(size_t)b * 128 + tid] = sqrtf(n2);
    }
}

extern "C" void kernel_launch(void* const* d_in, const int* in_sizes, int n_in,
                              void* d_out, int out_size, void* d_ws, size_t ws_size,
                              hipStream_t stream) {
    const float* x   = (const float*)d_in[0];
    const float* WS1 = (const float*)d_in[1];
    const float* WS2 = (const float*)d_in[2];
    const float* cw  = (const float*)d_in[3];
    float* out = (float*)d_out;

    char* ws = (char*)d_ws;
    float* m_buf = (float*)ws;                                  // 4 MiB
    float* votes = (float*)(ws + ((size_t)4 << 20));            // 8 MiB
    unsigned short* W1h = (unsigned short*)(ws + ((size_t)12 << 20));
    unsigned short* W1l = (unsigned short*)(ws + ((size_t)20 << 20));
    unsigned short* W2h = (unsigned short*)(ws + ((size_t)28 << 20));
    unsigned short* W2l = (unsigned short*)(ws + ((size_t)36 << 20));

    const size_t fixed = (size_t)44 << 20;
    const size_t perb  = (size_t)256 << 10;   // Hh per batch row (one plane)
    int CB = 128;
    if (ws_size < fixed + 128 * perb) {
        size_t avail = (ws_size > fixed) ? (ws_size - fixed) : perb;
        CB = (int)(avail / perb);
        if (CB < 1) CB = 1;
        if (CB > 128) CB = 128;
    }
    unsigned short* Hh = (unsigned short*)(ws + fixed);

    const int n4 = (8 * 512 * 1024) / 4;      // same count for WS1 and WS2
    hipLaunchKernelGGL(k0_split, dim3((n4 + 255) / 256), dim3(256), 0, stream,
                       WS1, W1h, W1l, n4);
    hipLaunchKernelGGL(k0_split, dim3((n4 + 255) / 256), dim3(256), 0, stream,
                       WS2, W2h, W2l, n4);

    for (int b0 = 0; b0 < 128; b0 += CB) {
        const int bc = (128 - b0 < CB) ? (128 - b0) : CB;
        for (int r = 0; r < 8; r++) {
            hipLaunchKernelGGL(k1_hbar_mfma, dim3(4, bc * 2), dim3(256), 0, stream,
                               x + (size_t)b0 * 256 * 1024,
                               W1h + (size_t)r * 512 * 1024,
                               W1l + (size_t)r * 512 * 1024,
                               Hh);
            hipLaunchKernelGGL(k2_mfma, dim3(16, bc), dim3(256), 0, stream,
                               Hh,
                               W2h + (size_t)r * 1024 * 512,
                               W2l + (size_t)r * 1024 * 512,
                               x, m_buf, b0, r);
        }
    }
    hipLaunchKernelGGL(k3_votes, dim3(16, 1, 8), dim3(256), 0, stream,
                       m_buf, cw, votes);
    hipLaunchKernelGGL(k4_routing, dim3(128), dim3(256), 0, stream,
                       votes, out);
}

// Round 4
// 1621.473 us; speedup vs baseline: 4.1516x; 1.3439x over previous
//
#include <hip/hip_runtime.h>

// CapsAll on MI355X — round 4: 1-pass bf16 MFMA for the two big GEMMs,
// MFMA k3, XCD-locality grid swizzles, x pre-converted to bf16.
//
// Error budget (calibrated on rounds 2->3): weights bf16-hi only in k1/k2
// adds ~+4e-7 absmax; expected total ~1.0e-6 vs 1.93e-6 threshold.
// cw stays split hi+lo (k3 2-pass) since k3 time is negligible.
//
//   k0h: fp32 -> bf16(hi) plane  (W1, W2, and x if ws allows)
//   k0t: cw [r][k][n] fp32 -> cwh/cwl [r][n][k] bf16 (tiled transpose+split)
//   k1:  hbar = relu(x @ WS1_r^T), 1 MFMA pass, out Hh bf16
//   k2:  scores = Hh @ WS2_r^T (256x64 reg tile) + fused col-softmax + m
//   k3:  votes = m @ cw, 2-pass MFMA (fallback: old fp32 VALU kernel)
//   k4:  dynamic routing (3 iters) + norms
//
// ws layout (MB): m 4 @0 | votes 8 @4 | W1h 8 @12 | W2h 8 @20 |
//   [cwh 32 @28 | cwl 32 @60]  if ws>=124 | [Xbf 64 @92] if ws>=188 |
//   Hh 32 @{156|92|28}  (b-chunked if tiny ws)

typedef __attribute__((ext_vector_type(8))) short bf16x8;
typedef __attribute__((ext_vector_type(8))) unsigned short u16x8;
typedef __attribute__((ext_vector_type(4))) float f32x4;

#define LDT 40  // LDS row stride in bf16 (80 B): 16B-aligned b128, 2-way banks

__device__ __forceinline__ unsigned short f2bf(float f) {
    unsigned u = __float_as_uint(f);
    u += 0x7FFF + ((u >> 16) & 1);           // round-to-nearest-even
    return (unsigned short)(u >> 16);
}
__device__ __forceinline__ float bf2f(unsigned short h) {
    return __uint_as_float(((unsigned)h) << 16);
}

// ---------------- k0h: elementwise fp32 -> bf16 hi plane ----------------
__global__ __launch_bounds__(256) void k0_hi(const float* __restrict__ src,
                                             unsigned short* __restrict__ hi,
                                             int n4) {
    int i = blockIdx.x * 256 + threadIdx.x;
    if (i >= n4) return;
    float4 v = ((const float4*)src)[i];
    ushort4 h;
    h.x = f2bf(v.x); h.y = f2bf(v.y); h.z = f2bf(v.z); h.w = f2bf(v.w);
    ((ushort4*)hi)[i] = h;
}

// ------- k0t: cw [r][k=1024][n=2048] fp32 -> [r][n][k] bf16 hi+lo -------
// 64x64 tiles through LDS. grid (32 n-tiles, 16 k-tiles, 8 r).
__global__ __launch_bounds__(256) void k0_tsplit(const float* __restrict__ cw,
                                                 unsigned short* __restrict__ ch,
                                                 unsigned short* __restrict__ cl) {
    __shared__ unsigned short Th[64 * 68], Tl[64 * 68];
    const int tid = threadIdx.x;
    const int n0 = blockIdx.x * 64, k0 = blockIdx.y * 64, r = blockIdx.z;
    const float* src = cw + (size_t)r * 1024 * 2048;
#pragma unroll
    for (int p = 0; p < 4; p++) {
        const int kl = p * 16 + (tid >> 4);
        const int nl = (tid & 15) * 4;
        float4 v = *(const float4*)(src + (size_t)(k0 + kl) * 2048 + n0 + nl);
        float vv[4] = {v.x, v.y, v.z, v.w};
#pragma unroll
        for (int e = 0; e < 4; e++) {
            unsigned short h = f2bf(vv[e]);
            Th[(nl + e) * 68 + kl] = h;
            Tl[(nl + e) * 68 + kl] = f2bf(vv[e] - bf2f(h));
        }
    }
    __syncthreads();
    const int nl = tid >> 2, kl = (tid & 3) * 16;
    unsigned short* dh = ch + ((size_t)r * 2048 + n0 + nl) * 1024 + k0 + kl;
    unsigned short* dl = cl + ((size_t)r * 2048 + n0 + nl) * 1024 + k0 + kl;
    *(u16x8*)(dh)     = *(const u16x8*)&Th[nl * 68 + kl];
    *(u16x8*)(dh + 8) = *(const u16x8*)&Th[nl * 68 + kl + 8];
    *(u16x8*)(dl)     = *(const u16x8*)&Tl[nl * 68 + kl];
    *(u16x8*)(dl + 8) = *(const u16x8*)&Tl[nl * 68 + kl + 8];
}

// ---------------- k1: hbar = relu(x @ W1^T), 1-pass bf16 ----------------
// XBF=1: X already bf16 [M x 1024]; XBF=0: X fp32, convert inline.
// 128x128 tile, BK=32, 4 waves (2x2 of 64x64). grid (m-tiles, 4): id%8==m%8
// so the 4 n-blocks sharing an X m-slice land on one XCD.
template <int XBF>
__global__ __launch_bounds__(256) void k1_hbar_mfma(
    const void* __restrict__ Xv,
    const unsigned short* __restrict__ Wh,
    unsigned short* __restrict__ Hh) {
    __shared__ unsigned short Ah[128 * LDT];
    __shared__ unsigned short Bh[128 * LDT];
    const int tid = threadIdx.x;
    const int m0 = blockIdx.x * 128, n0 = blockIdx.y * 128;
    const int wave = tid >> 6, lane = tid & 63;
    const int wm = (wave >> 1) * 64, wn = (wave & 1) * 64;
    const int lx = lane & 15, qd = lane >> 4;
    const int srow = tid >> 1, scol = (tid & 1) * 16;

    f32x4 acc[4][4];
#pragma unroll
    for (int i = 0; i < 4; i++)
#pragma unroll
        for (int j = 0; j < 4; j++) acc[i][j] = (f32x4){0.f, 0.f, 0.f, 0.f};

    const unsigned short* whrow = Wh + (size_t)(n0 + srow) * 1024 + scol;
    unsigned short* ah = &Ah[srow * LDT + scol];
    unsigned short* bh = &Bh[srow * LDT + scol];

    for (int k0 = 0; k0 < 1024; k0 += 32) {
        if (XBF) {
            const unsigned short* xrow =
                (const unsigned short*)Xv + (size_t)(m0 + srow) * 1024 + scol;
            u16x8 a0 = *(const u16x8*)(xrow + k0);
            u16x8 a1 = *(const u16x8*)(xrow + k0 + 8);
            *(u16x8*)(ah) = a0; *(u16x8*)(ah + 8) = a1;
        } else {
            const float* xrow = (const float*)Xv + (size_t)(m0 + srow) * 1024 + scol;
            float4 v0 = *(const float4*)(xrow + k0);
            float4 v1 = *(const float4*)(xrow + k0 + 4);
            float4 v2 = *(const float4*)(xrow + k0 + 8);
            float4 v3 = *(const float4*)(xrow + k0 + 12);
            float vv[16] = {v0.x, v0.y, v0.z, v0.w, v1.x, v1.y, v1.z, v1.w,
                            v2.x, v2.y, v2.z, v2.w, v3.x, v3.y, v3.z, v3.w};
            u16x8 p0, p1;
#pragma unroll
            for (int e = 0; e < 8; e++) p0[e] = f2bf(vv[e]);
#pragma unroll
            for (int e = 0; e < 8; e++) p1[e] = f2bf(vv[8 + e]);
            *(u16x8*)(ah) = p0; *(u16x8*)(ah + 8) = p1;
        }
        u16x8 b0 = *(const u16x8*)(whrow + k0);
        u16x8 b1 = *(const u16x8*)(whrow + k0 + 8);
        *(u16x8*)(bh) = b0; *(u16x8*)(bh + 8) = b1;
        __syncthreads();

        bf16x8 fa[4], fb[4];
#pragma unroll
        for (int i = 0; i < 4; i++) {
            fa[i] = *(const bf16x8*)&Ah[(wm + 16 * i + lx) * LDT + 8 * qd];
            fb[i] = *(const bf16x8*)&Bh[(wn + 16 * i + lx) * LDT + 8 * qd];
        }
#pragma unroll
        for (int i = 0; i < 4; i++)
#pragma unroll
            for (int j = 0; j < 4; j++)
                acc[i][j] = __builtin_amdgcn_mfma_f32_16x16x32_bf16(fa[i], fb[j], acc[i][j], 0, 0, 0);
        __syncthreads();
    }

#pragma unroll
    for (int i = 0; i < 4; i++)
#pragma unroll
        for (int j = 0; j < 4; j++) {
            const int col = n0 + wn + 16 * j + lx;
#pragma unroll
            for (int p = 0; p < 4; p++) {
                const int row = m0 + wm + 16 * i + 4 * qd + p;
                Hh[(size_t)row * 512 + col] = f2bf(fmaxf(acc[i][j][p], 0.f));
            }
        }
}

// ------- k2: scores (256x64 reg tile) + column softmax over t + m -------
// 1-pass bf16. grid (b-blocks, 16 u): id%8==b%8, so all 16 u-blocks sharing
// one Hh b-slice land on one XCD.
__global__ __launch_bounds__(256) void k2_mfma(
    const unsigned short* __restrict__ Hh,
    const unsigned short* __restrict__ W2h,
    const float* __restrict__ x, float* __restrict__ m_out, int b0, int r) {
    __shared__ unsigned short Ah[256 * LDT];
    __shared__ unsigned short Bh[64 * LDT];
    __shared__ float mred[4 * 64], sred[4 * 64], pred[4 * 64];
    const int tid = threadIdx.x;
    const int b_local = blockIdx.x, b = b0 + b_local;
    const int u0 = blockIdx.y * 64;
    const int wave = tid >> 6, lane = tid & 63;
    const int lx = lane & 15, qd = lane >> 4;

    const unsigned short* ahrow = Hh + (size_t)(b_local * 256 + tid) * 512;
    const int brow = tid >> 2, bcol = (tid & 3) * 8;
    const unsigned short* bhrow = W2h + (size_t)(u0 + brow) * 512 + bcol;

    f32x4 acc[4][4];
#pragma unroll
    for (int i = 0; i < 4; i++)
#pragma unroll
        for (int j = 0; j < 4; j++) acc[i][j] = (f32x4){0.f, 0.f, 0.f, 0.f};

    for (int k0 = 0; k0 < 512; k0 += 32) {
        u16x8 a0 = *(const u16x8*)(ahrow + k0);
        u16x8 a1 = *(const u16x8*)(ahrow + k0 + 8);
        u16x8 a2 = *(const u16x8*)(ahrow + k0 + 16);
        u16x8 a3 = *(const u16x8*)(ahrow + k0 + 24);
        *(u16x8*)&Ah[tid * LDT + 0] = a0;  *(u16x8*)&Ah[tid * LDT + 8] = a1;
        *(u16x8*)&Ah[tid * LDT + 16] = a2; *(u16x8*)&Ah[tid * LDT + 24] = a3;
        *(u16x8*)&Bh[brow * LDT + bcol] = *(const u16x8*)(bhrow + k0);
        __syncthreads();

        bf16x8 fa[4], fb[4];
#pragma unroll
        for (int i = 0; i < 4; i++) {
            fa[i] = *(const bf16x8*)&Ah[(64 * wave + 16 * i + lx) * LDT + 8 * qd];
            fb[i] = *(const bf16x8*)&Bh[(16 * i + lx) * LDT + 8 * qd];
        }
#pragma unroll
        for (int i = 0; i < 4; i++)
#pragma unroll
            for (int j = 0; j < 4; j++)
                acc[i][j] = __builtin_amdgcn_mfma_f32_16x16x32_bf16(fa[i], fb[j], acc[i][j], 0, 0, 0);
        __syncthreads();
    }

    // ---- column max over t: per-lane -> cross-quad -> cross-wave ----
    float cm[4];
#pragma unroll
    for (int j = 0; j < 4; j++) {
        float mx = acc[0][j][0];
#pragma unroll
        for (int i = 0; i < 4; i++)
#pragma unroll
            for (int p = 0; p < 4; p++) mx = fmaxf(mx, acc[i][j][p]);
        mx = fmaxf(mx, __shfl_xor(mx, 16, 64));
        mx = fmaxf(mx, __shfl_xor(mx, 32, 64));
        if (qd == 0) mred[wave * 64 + 16 * j + lx] = mx;
    }
    __syncthreads();
#pragma unroll
    for (int j = 0; j < 4; j++) {
        const int c = 16 * j + lx;
        cm[j] = fmaxf(fmaxf(mred[c], mred[64 + c]), fmaxf(mred[128 + c], mred[192 + c]));
    }

    // ---- exp + weighted sum against x ----
    float ds[4] = {0.f, 0.f, 0.f, 0.f}, pm[4] = {0.f, 0.f, 0.f, 0.f};
    const float* xb = x + (size_t)b * 256 * 1024 + u0;
#pragma unroll
    for (int i = 0; i < 4; i++) {
#pragma unroll
        for (int p = 0; p < 4; p++) {
            const int t = 64 * wave + 16 * i + 4 * qd + p;
            const float* xr = xb + (size_t)t * 1024;
            float xv[4];
#pragma unroll
            for (int j = 0; j < 4; j++) xv[j] = xr[16 * j + lx];
#pragma unroll
            for (int j = 0; j < 4; j++) {
                float e = expf(acc[i][j][p] - cm[j]);
                ds[j] += e;
                pm[j] += e * xv[j];
            }
        }
    }
#pragma unroll
    for (int j = 0; j < 4; j++) {
        ds[j] += __shfl_xor(ds[j], 16, 64);
        ds[j] += __shfl_xor(ds[j], 32, 64);
        pm[j] += __shfl_xor(pm[j], 16, 64);
        pm[j] += __shfl_xor(pm[j], 32, 64);
        if (qd == 0) {
            sred[wave * 64 + 16 * j + lx] = ds[j];
            pred[wave * 64 + 16 * j + lx] = pm[j];
        }
    }
    __syncthreads();
    if (tid < 64) {
        float dsum = sred[tid] + sred[64 + tid] + sred[128 + tid] + sred[192 + tid];
        float psum = pred[tid] + pred[64 + tid] + pred[128 + tid] + pred[192 + tid];
        m_out[(size_t)(r * 128 + b) * 1024 + u0 + tid] = psum / dsum;
    }
}

// ------- k3 (MFMA): votes = m @ cw, cw split [r][n][k] hi/lo, 2-pass -------
// BM=128, BN=64, BK=32. grid (8 r, 32 n): id%8==r, so all n-blocks sharing
// one m_r slice land on one XCD.
__global__ __launch_bounds__(256) void k3_votes_mfma(
    const float* __restrict__ Mb,
    const unsigned short* __restrict__ CWh,
    const unsigned short* __restrict__ CWl,
    float* __restrict__ V) {
    __shared__ unsigned short Ah[128 * LDT];
    __shared__ unsigned short Bh[64 * LDT], Bl[64 * LDT];
    const int tid = threadIdx.x;
    const int r = blockIdx.x, n0 = blockIdx.y * 64;
    const int wave = tid >> 6, lane = tid & 63;
    const int wr = wave >> 1, wc = wave & 1;
    const int lx = lane & 15, qd = lane >> 4;
    const int srow = tid >> 1, scol = (tid & 1) * 16;
    const int brow = tid >> 2, bcol = (tid & 3) * 8;

    const float* arow = Mb + (size_t)(r * 128 + srow) * 1024 + scol;
    const unsigned short* bhrow = CWh + ((size_t)r * 2048 + n0 + brow) * 1024 + bcol;
    const unsigned short* blrow = CWl + ((size_t)r * 2048 + n0 + brow) * 1024 + bcol;

    f32x4 acc[4][2];
#pragma unroll
    for (int i = 0; i < 4; i++)
#pragma unroll
        for (int j = 0; j < 2; j++) acc[i][j] = (f32x4){0.f, 0.f, 0.f, 0.f};

    for (int k0 = 0; k0 < 1024; k0 += 32) {
        float4 v0 = *(const float4*)(arow + k0);
        float4 v1 = *(const float4*)(arow + k0 + 4);
        float4 v2 = *(const float4*)(arow + k0 + 8);
        float4 v3 = *(const float4*)(arow + k0 + 12);
        float vv[16] = {v0.x, v0.y, v0.z, v0.w, v1.x, v1.y, v1.z, v1.w,
                        v2.x, v2.y, v2.z, v2.w, v3.x, v3.y, v3.z, v3.w};
        u16x8 p0, p1;
#pragma unroll
        for (int e = 0; e < 8; e++) p0[e] = f2bf(vv[e]);
#pragma unroll
        for (int e = 0; e < 8; e++) p1[e] = f2bf(vv[8 + e]);
        *(u16x8*)&Ah[srow * LDT + scol] = p0;
        *(u16x8*)&Ah[srow * LDT + scol + 8] = p1;
        *(u16x8*)&Bh[brow * LDT + bcol] = *(const u16x8*)(bhrow + k0);
        *(u16x8*)&Bl[brow * LDT + bcol] = *(const u16x8*)(blrow + k0);
        __syncthreads();

        bf16x8 fa[4], fbh[2], fbl[2];
#pragma unroll
        for (int i = 0; i < 4; i++)
            fa[i] = *(const bf16x8*)&Ah[(64 * wr + 16 * i + lx) * LDT + 8 * qd];
#pragma unroll
        for (int j = 0; j < 2; j++) {
            fbh[j] = *(const bf16x8*)&Bh[(32 * wc + 16 * j + lx) * LDT + 8 * qd];
            fbl[j] = *(const bf16x8*)&Bl[(32 * wc + 16 * j + lx) * LDT + 8 * qd];
        }
#pragma unroll
        for (int i = 0; i < 4; i++)
#pragma unroll
            for (int j = 0; j < 2; j++)
                acc[i][j] = __builtin_amdgcn_mfma_f32_16x16x32_bf16(fa[i], fbh[j], acc[i][j], 0, 0, 0);
#pragma unroll
        for (int i = 0; i < 4; i++)
#pragma unroll
            for (int j = 0; j < 2; j++)
                acc[i][j] = __builtin_amdgcn_mfma_f32_16x16x32_bf16(fa[i], fbl[j], acc[i][j], 0, 0, 0);
        __syncthreads();
    }

#pragma unroll
    for (int i = 0; i < 4; i++)
#pragma unroll
        for (int j = 0; j < 2; j++) {
            const int col = n0 + 32 * wc + 16 * j + lx;
#pragma unroll
            for (int p = 0; p < 4; p++) {
                const int row = 64 * wr + 16 * i + 4 * qd + p;
                V[((size_t)r * 128 + row) * 2048 + col] = acc[i][j][p];
            }
        }
}

// ---------------- k3 fallback: fp32 VALU (small-ws path) ----------------
__global__ __launch_bounds__(256) void k3_votes(const float* __restrict__ Mb,
                                                const float* __restrict__ CW,
                                                float* __restrict__ V) {
    __shared__ float As[16][132];
    __shared__ float Bs[16][132];
    const int tid = threadIdx.x;
    const int r = blockIdx.z;
    const int n0 = blockIdx.x * 128;
    const float* A = Mb + (size_t)r * 128 * 1024;
    const float* Bm = CW + (size_t)r * 1024 * 2048;
    float* C = V + (size_t)r * 128 * 2048;
    const int ty = tid >> 4, tx = tid & 15;
    const int k4 = (tid & 3) * 4, row = tid >> 2;
    const int n4 = (tid & 31) * 4, krow = tid >> 5;

    float acc[8][8];
#pragma unroll
    for (int i = 0; i < 8; i++)
#pragma unroll
        for (int j = 0; j < 8; j++) acc[i][j] = 0.f;

    for (int k0 = 0; k0 < 1024; k0 += 16) {
#pragma unroll
        for (int rr = 0; rr < 2; rr++) {
            const int m = row + rr * 64;
            float4 av = *(const float4*)(A + (size_t)m * 1024 + k0 + k4);
            As[k4 + 0][m] = av.x; As[k4 + 1][m] = av.y;
            As[k4 + 2][m] = av.z; As[k4 + 3][m] = av.w;
            const int k = krow + rr * 8;
            float4 bv = *(const float4*)(Bm + (size_t)(k0 + k) * 2048 + n0 + n4);
            *(float4*)(&Bs[k][n4]) = bv;
        }
        __syncthreads();
#pragma unroll
        for (int k = 0; k < 16; k++) {
            float a[8], b[8];
            *(float4*)(a)     = *(const float4*)(&As[k][ty * 8]);
            *(float4*)(a + 4) = *(const float4*)(&As[k][ty * 8 + 4]);
            *(float4*)(b)     = *(const float4*)(&Bs[k][tx * 8]);
            *(float4*)(b + 4) = *(const float4*)(&Bs[k][tx * 8 + 4]);
#pragma unroll
            for (int i = 0; i < 8; i++)
#pragma unroll
                for (int j = 0; j < 8; j++) acc[i][j] += a[i] * b[j];
        }
        __syncthreads();
    }
#pragma unroll
    for (int i = 0; i < 8; i++) {
        const int m = ty * 8 + i;
#pragma unroll
        for (int j = 0; j < 8; j += 4) {
            float4 v;
            v.x = acc[i][j + 0]; v.y = acc[i][j + 1];
            v.z = acc[i][j + 2]; v.w = acc[i][j + 3];
            *(float4*)(C + (size_t)m * 2048 + n0 + tx * 8 + j) = v;
        }
    }
}

// ---------------- k4: dynamic routing ----------------
__global__ __launch_bounds__(256) void k4_routing(const float* __restrict__ V,
                                                  float* __restrict__ out) {
    __shared__ float logits[8 * 128];
    __shared__ float route[8 * 128];
    __shared__ float preact[128 * 16];
    __shared__ float act[128 * 16];
    __shared__ float fred[128];
    const int b = blockIdx.x, tid = threadIdx.x;
    const float* vb = V + (size_t)b * 2048;

    for (int i = tid; i < 1024; i += 256) logits[i] = 0.f;
    __syncthreads();

    for (int it = 0; it < 3; it++) {
        {
            const int r = tid >> 5, g = tid & 31;
            float l[4];
#pragma unroll
            for (int q = 0; q < 4; q++) l[q] = logits[r * 128 + g + q * 32];
            float mx = fmaxf(fmaxf(l[0], l[1]), fmaxf(l[2], l[3]));
            for (int msk = 16; msk; msk >>= 1) mx = fmaxf(mx, __shfl_xor(mx, msk, 32));
            float e[4], s = 0.f;
#pragma unroll
            for (int q = 0; q < 4; q++) { e[q] = expf(l[q] - mx); s += e[q]; }
            for (int msk = 16; msk; msk >>= 1) s += __shfl_xor(s, msk, 32);
            float inv = 1.f / s;
#pragma unroll
            for (int q = 0; q < 4; q++) route[r * 128 + g + q * 32] = e[q] * inv;
        }
        __syncthreads();
        for (int i = tid; i < 2048; i += 256) {
            const int c = i >> 4;
            float a = 0.f;
#pragma unroll
            for (int r = 0; r < 8; r++)
                a += route[r * 128 + c] * vb[(size_t)r * 128 * 2048 + i];
            preact[i] = a;
        }
        __syncthreads();
        if (tid < 128) {
            float n2 = 0.f;
#pragma unroll
            for (int o = 0; o < 16; o++) { float p = preact[tid * 16 + o]; n2 += p * p; }
            fred[tid] = sqrtf(n2) / (1.f + n2);
        }
        __syncthreads();
        for (int i = tid; i < 2048; i += 256) act[i] = preact[i] * fred[i >> 4];
        __syncthreads();
        for (int i = tid; i < 1024; i += 256) {
            const int r = i >> 7, c = i & 127;
            float d = 0.f;
#pragma unroll
            for (int o = 0; o < 16; o++)
                d += vb[(size_t)r * 128 * 2048 + c * 16 + o] * act[c * 16 + o];
            logits[i] += d;
        }
        __syncthreads();
    }
    if (tid < 128) {
        float n2 = 0.f;
#pragma unroll
        for (int o = 0; o < 16; o++) { float a = act[tid * 16 + o]; n2 += a * a; }
        out[(size_t)b * 128 + tid] = sqrtf(n2);
    }
}

extern "C" void kernel_launch(void* const* d_in, const int* in_sizes, int n_in,
                              void* d_out, int out_size, void* d_ws, size_t ws_size,
                              hipStream_t stream) {
    const float* x   = (const float*)d_in[0];
    const float* WS1 = (const float*)d_in[1];
    const float* WS2 = (const float*)d_in[2];
    const float* cw  = (const float*)d_in[3];
    float* out = (float*)d_out;

    char* ws = (char*)d_ws;
    float* m_buf = (float*)ws;                                      // 4 MiB
    float* votes = (float*)(ws + ((size_t)4 << 20));                // 8 MiB
    unsigned short* W1h = (unsigned short*)(ws + ((size_t)12 << 20)); // 8 MiB
    unsigned short* W2h = (unsigned short*)(ws + ((size_t)20 << 20)); // 8 MiB

    const bool use_cw  = ws_size >= ((size_t)124 << 20);
    const bool use_xbf = ws_size >= ((size_t)188 << 20);
    unsigned short* CWh = (unsigned short*)(ws + ((size_t)28 << 20)); // 32 MiB
    unsigned short* CWl = (unsigned short*)(ws + ((size_t)60 << 20)); // 32 MiB
    unsigned short* Xbf = (unsigned short*)(ws + ((size_t)92 << 20)); // 64 MiB
    const size_t hh_off = use_xbf ? ((size_t)156 << 20)
                        : use_cw  ? ((size_t)92 << 20)
                                  : ((size_t)28 << 20);
    unsigned short* Hh = (unsigned short*)(ws + hh_off);

    int CB = 128;
    {
        const size_t perb = (size_t)256 << 10;  // Hh per batch row
        if (ws_size < hh_off + 128 * perb) {
            size_t avail = (ws_size > hh_off) ? (ws_size - hh_off) : perb;
            CB = (int)(avail / perb);
            if (CB < 1) CB = 1;
            if (CB > 128) CB = 128;
        }
    }

    const int nW4 = (8 * 512 * 1024) / 4;
    k0_hi<<<dim3((nW4 + 255) / 256), dim3(256), 0, stream>>>(WS1, W1h, nW4);
    k0_hi<<<dim3((nW4 + 255) / 256), dim3(256), 0, stream>>>(WS2, W2h, nW4);
    if (use_cw)
        k0_tsplit<<<dim3(32, 16, 8), dim3(256), 0, stream>>>(cw, CWh, CWl);
    if (use_xbf) {
        const int nX4 = (128 * 256 * 1024) / 4;
        k0_hi<<<dim3((nX4 + 255) / 256), dim3(256), 0, stream>>>(x, Xbf, nX4);
    }

    for (int b0 = 0; b0 < 128; b0 += CB) {
        const int bc = (128 - b0 < CB) ? (128 - b0) : CB;
        for (int r = 0; r < 8; r++) {
            if (use_xbf)
                k1_hbar_mfma<1><<<dim3(bc * 2, 4), dim3(256), 0, stream>>>(
                    (const void*)(Xbf + (size_t)b0 * 256 * 1024),
                    W1h + (size_t)r * 512 * 1024, Hh);
            else
                k1_hbar_mfma<0><<<dim3(bc * 2, 4), dim3(256), 0, stream>>>(
                    (const void*)(x + (size_t)b0 * 256 * 1024),
                    W1h + (size_t)r * 512 * 1024, Hh);
            k2_mfma<<<dim3(bc, 16), dim3(256), 0, stream>>>(
                Hh, W2h + (size_t)r * 1024 * 512, x, m_buf, b0, r);
        }
    }
    if (use_cw)
        k3_votes_mfma<<<dim3(8, 32), dim3(256), 0, stream>>>(m_buf, CWh, CWl, votes);
    else
        k3_votes<<<dim3(16, 1, 8), dim3(256), 0, stream>>>(m_buf, cw, votes);
    k4_routing<<<dim3(128), dim3(256), 0, stream>>>(votes, out);
}